// Round 1
// baseline (58.726 us; speedup 1.0000x reference)
//
#include <hip/hip_runtime.h>
#include <hip/hip_bf16.h>

#define BB 4096
#define SS 128
#define DIMQ 512
#define DIMZ 64
#define DIMU 512
#define HIDV 512

typedef __attribute__((ext_vector_type(8))) short sh8;
typedef __attribute__((ext_vector_type(4))) float f32x4;

__device__ inline unsigned short f2bf(float f) {
    unsigned u = __float_as_uint(f);
    unsigned r = (u + 0x7fffu + ((u >> 16) & 1u)) >> 16;
    return (unsigned short)r;
}

// c[h] = b1[h] + sum_k z[k] * W1[(DIMQ+k)*HIDV + h]
__global__ void k_prep_c(const float* __restrict__ z, const float* __restrict__ W1,
                         const float* __restrict__ b1, float* __restrict__ c) {
    int h = blockIdx.x * blockDim.x + threadIdx.x;
    if (h >= HIDV) return;
    float acc = b1[h];
    #pragma unroll 8
    for (int k = 0; k < DIMZ; k++) acc += z[k] * W1[(DIMQ + k) * HIDV + h];
    c[h] = acc;
}

// W1qT[n][k] = bf16(W1[k][n]) for k<512 (transpose first 512 rows)
__global__ void k_transpose_w1(const float* __restrict__ W1, unsigned short* __restrict__ W1qT) {
    __shared__ float tile[32][33];
    int k0 = blockIdx.y * 32, n0 = blockIdx.x * 32;
    tile[threadIdx.y][threadIdx.x] = W1[(size_t)(k0 + threadIdx.y) * HIDV + n0 + threadIdx.x];
    __syncthreads();
    W1qT[(size_t)(n0 + threadIdx.y) * DIMQ + k0 + threadIdx.x] = f2bf(tile[threadIdx.x][threadIdx.y]);
}

// Per batch row: offline closed-form, online 10-step scan, 8 sums of squares,
// bf16 GEMM inputs (Qall rows: [b]=q0_off, [B+b]=qf_off, [2B+b]=q0_on, [3B+b]=qf2),
// KV[e*B+b] = 0.5*sum(p^2) + 0.05*sum(q^2), qtraj output.
__global__ __launch_bounds__(256) void k_states(
        const float* __restrict__ u, const float* __restrict__ q0off,
        const float* __restrict__ p0off, const float* __restrict__ q0on,
        const float* __restrict__ p0on, unsigned short* __restrict__ Qall,
        float* __restrict__ KV, float* __restrict__ qtraj,
        float R00, float R01, float R10, float R11) {
    int b = blockIdx.x;
    int t = threadIdx.x;
    float sums[8] = {0, 0, 0, 0, 0, 0, 0, 0};
    #pragma unroll
    for (int e = 0; e < 2; e++) {
        int j = t + e * 256;
        size_t idx = (size_t)b * DIMQ + j;
        float q = q0off[idx], p = p0off[idx];
        sums[0] += q * q;
        sums[1] += p * p;
        float qf = R00 * q + R01 * p;
        float pf = R10 * q + R11 * p;
        sums[2] += qf * qf;
        sums[3] += pf * pf;
        Qall[idx] = f2bf(q);
        Qall[(size_t)(BB + b) * DIMQ + j] = f2bf(qf);

        float q2 = q0on[idx], p2 = p0on[idx];
        sums[4] += q2 * q2;
        sums[5] += p2 * p2;
        Qall[(size_t)(2 * BB + b) * DIMQ + j] = f2bf(q2);
        const float* ub = u + (size_t)b * SS * DIMU + j;
        #pragma unroll
        for (int st = 0; st < 10; st++) {
            float uv = ub[(size_t)st * DIMU];
            p2 = (p2 - 0.1f * (0.1f * q2) + 0.1f * (0.1f * uv)) * 0.99f;
            q2 = q2 + 0.1f * p2;
        }
        sums[6] += q2 * q2;
        sums[7] += p2 * p2;
        Qall[(size_t)(3 * BB + b) * DIMQ + j] = f2bf(q2);
        qtraj[idx] = q2;
    }
    __shared__ float red[4][8];
    int lane = t & 63, w = t >> 6;
    #pragma unroll
    for (int k = 0; k < 8; k++) {
        float v = sums[k];
        #pragma unroll
        for (int m = 1; m < 64; m <<= 1) v += __shfl_xor(v, m, 64);
        if (lane == 0) red[w][k] = v;
    }
    __syncthreads();
    if (t < 4) {
        int e = t;
        float sq = red[0][2 * e] + red[1][2 * e] + red[2][2 * e] + red[3][2 * e];
        float sp = red[0][2 * e + 1] + red[1][2 * e + 1] + red[2][2 * e + 1] + red[3][2 * e + 1];
        KV[(size_t)e * BB + b] = 0.5f * sp + 0.05f * sq;
    }
}

// GEMM: Qall(16384x512 bf16) @ W1qT^T(512x512) with fused tanh(.+c)*W2 row-reduce
// epilogue -> atomicAdd into Vnet[row]. 128x128 block tile, 4 waves (2x2 of 64x64).
__global__ __launch_bounds__(256) void k_gemm(
        const unsigned short* __restrict__ Qall, const unsigned short* __restrict__ W1qT,
        const float* __restrict__ cvec, const float* __restrict__ W2,
        float* __restrict__ Vnet) {
    __shared__ __attribute__((aligned(16))) char lds[32768];
    char* ldsA = lds;
    char* ldsB = lds + 16384;
    const int t = threadIdx.x;
    const int lane = t & 63;
    const int w = t >> 6;
    const int wr = w >> 1, wc = w & 1;
    const int rowBase = blockIdx.x * 128;
    const int colBase = blockIdx.y * 128;

    f32x4 acc[4][4] = {};

    for (int kt = 0; kt < 8; kt++) {
        __syncthreads();
        // stage A and B tiles: [128 rows][64 bf16] each, XOR-swizzled via source addr
        #pragma unroll
        for (int i = 0; i < 4; i++) {
            unsigned chunk = i * 256 + t;      // 0..1023, 16B each
            unsigned r = chunk >> 3;           // LDS row 0..127
            unsigned cb = chunk & 7;           // 16B column slot in 128B row
            unsigned scb = cb ^ (r & 7);       // inverse-swizzled source slot
            const unsigned short* srcA = Qall + (size_t)(rowBase + r) * 512 + (unsigned)kt * 64 + scb * 8;
            __builtin_amdgcn_global_load_lds(
                (const __attribute__((address_space(1))) unsigned int*)(const void*)srcA,
                (__attribute__((address_space(3))) unsigned int*)(void*)(ldsA + chunk * 16), 16, 0, 0);
            const unsigned short* srcB = W1qT + (size_t)(colBase + r) * 512 + (unsigned)kt * 64 + scb * 8;
            __builtin_amdgcn_global_load_lds(
                (const __attribute__((address_space(1))) unsigned int*)(const void*)srcB,
                (__attribute__((address_space(3))) unsigned int*)(void*)(ldsB + chunk * 16), 16, 0, 0);
        }
        __syncthreads();
        #pragma unroll
        for (int ks = 0; ks < 2; ks++) {
            sh8 af[4], bf_[4];
            int kb = ks * 64 + ((lane >> 4) << 4);
            #pragma unroll
            for (int mi = 0; mi < 4; mi++) {
                int m = wr * 64 + mi * 16 + (lane & 15);
                int addr = m * 128 + (kb ^ ((m & 7) << 4));
                af[mi] = *(const sh8*)(ldsA + addr);
            }
            #pragma unroll
            for (int ni = 0; ni < 4; ni++) {
                int n = wc * 64 + ni * 16 + (lane & 15);
                int addr = n * 128 + (kb ^ ((n & 7) << 4));
                bf_[ni] = *(const sh8*)(ldsB + addr);
            }
            #pragma unroll
            for (int mi = 0; mi < 4; mi++)
                #pragma unroll
                for (int ni = 0; ni < 4; ni++)
                    acc[mi][ni] = __builtin_amdgcn_mfma_f32_16x16x32_bf16(af[mi], bf_[ni], acc[mi][ni], 0, 0, 0);
        }
    }

    // epilogue: Vnet_partial[row] = sum_n tanh(acc + c[n]) * W2[n]
    float w2v[4], cv[4];
    #pragma unroll
    for (int ni = 0; ni < 4; ni++) {
        int n = colBase + wc * 64 + ni * 16 + (lane & 15);
        w2v[ni] = W2[n];
        cv[ni] = cvec[n];
    }
    #pragma unroll
    for (int mi = 0; mi < 4; mi++) {
        #pragma unroll
        for (int r = 0; r < 4; r++) {
            float partial = 0.f;
            #pragma unroll
            for (int ni = 0; ni < 4; ni++)
                partial += tanhf(acc[mi][ni][r] + cv[ni]) * w2v[ni];
            partial += __shfl_xor(partial, 1, 64);
            partial += __shfl_xor(partial, 2, 64);
            partial += __shfl_xor(partial, 4, 64);
            partial += __shfl_xor(partial, 8, 64);
            if ((lane & 15) == 0) {
                int row = rowBase + wr * 64 + mi * 16 + ((lane >> 4) << 2) + r;
                atomicAdd(Vnet + row, partial);
            }
        }
    }
}

__global__ void k_final(const float* __restrict__ KV, const float* __restrict__ Vnet,
                        const float* __restrict__ b2, float* __restrict__ out) {
    int i = blockIdx.x * blockDim.x + threadIdx.x;
    if (i >= 4 * BB) return;
    int e = i >> 12;       // /4096: 0=F0_off 1=Ff_off 2=F0_on 3=Ff_on
    int b = i & 4095;
    float F = KV[i] + Vnet[i] + b2[0];
    size_t o;
    if (e == 0) o = (size_t)b * 2;
    else if (e == 1) o = (size_t)b * 2 + 1;
    else if (e == 2) o = 2 * BB + (size_t)b * 2;
    else o = 2 * BB + (size_t)b * 2 + 1;
    out[o] = F;
}

extern "C" void kernel_launch(void* const* d_in, const int* in_sizes, int n_in,
                              void* d_out, int out_size, void* d_ws, size_t ws_size,
                              hipStream_t stream) {
    const float* u     = (const float*)d_in[0];
    const float* q0off = (const float*)d_in[1];
    const float* p0off = (const float*)d_in[2];
    const float* q0on  = (const float*)d_in[3];
    const float* p0on  = (const float*)d_in[4];
    const float* z     = (const float*)d_in[5];
    const float* W1    = (const float*)d_in[6];
    const float* b1    = (const float*)d_in[7];
    const float* W2    = (const float*)d_in[8];
    const float* b2    = (const float*)d_in[9];
    float* out = (float*)d_out;

    char* ws = (char*)d_ws;
    unsigned short* Qall = (unsigned short*)ws;                        // 16 MB
    unsigned short* W1qT = (unsigned short*)(ws + 16777216);           // 512 KB
    float* cvec = (float*)(ws + 16777216 + 524288);                    // 2 KB
    float* KV   = (float*)(ws + 16777216 + 524288 + 2048);             // 64 KB
    float* Vnet = (float*)(ws + 16777216 + 524288 + 2048 + 65536);     // 64 KB

    // offline propagator M^19 (double): q' = q + 0.1 p ; p' = 0.99 p - 0.0099 q
    double a00 = 1, a01 = 0, a10 = 0, a11 = 1;
    const double m00 = 1.0, m01 = 0.1, m10 = -0.1 * 0.1 * 0.99, m11 = 0.99;
    for (int i = 0; i < 19; i++) {
        double n00 = m00 * a00 + m01 * a10;
        double n01 = m00 * a01 + m01 * a11;
        double n10 = m10 * a00 + m11 * a10;
        double n11 = m10 * a01 + m11 * a11;
        a00 = n00; a01 = n01; a10 = n10; a11 = n11;
    }

    hipMemsetAsync(Vnet, 0, 4 * BB * sizeof(float), stream);
    k_prep_c<<<2, 256, 0, stream>>>(z, W1, b1, cvec);
    k_transpose_w1<<<dim3(16, 16), dim3(32, 32), 0, stream>>>(W1, W1qT);
    k_states<<<BB, 256, 0, stream>>>(u, q0off, p0off, q0on, p0on, Qall, KV,
                                     out + 4 * BB, (float)a00, (float)a01, (float)a10, (float)a11);
    k_gemm<<<dim3(128, 4), 256, 0, stream>>>(Qall, W1qT, cvec, W2, Vnet);
    k_final<<<64, 256, 0, stream>>>(KV, Vnet, b2, out);
}

// Round 2
// 48.614 us; speedup vs baseline: 1.2080x; 1.2080x over previous
//
#include <hip/hip_runtime.h>
#include <hip/hip_bf16.h>

#define BB 4096
#define SS 128
#define DIMQ 512
#define DIMZ 64
#define DIMU 512
#define HIDV 512

typedef __attribute__((ext_vector_type(8))) short sh8;
typedef __attribute__((ext_vector_type(4))) float f32x4;
typedef __attribute__((ext_vector_type(4))) unsigned short us4;

__device__ inline unsigned short f2bf(float f) {
    unsigned u = __float_as_uint(f);
    return (unsigned short)((u + 0x7fffu + ((u >> 16) & 1u)) >> 16);
}

// Fused prep: W1qT[n][k] = bf16(W1[k][n]) for k<512, plus c[h] = b1[h] + z @ W1[512:576, h]
__global__ __launch_bounds__(256) void k_prep(const float* __restrict__ W1,
        const float* __restrict__ z, const float* __restrict__ b1,
        unsigned short* __restrict__ W1qT, float* __restrict__ cvec) {
    __shared__ float tile[32][33];
    int bx = blockIdx.x & 15, by = blockIdx.x >> 4;
    int k0 = by * 32, n0 = bx * 32;
    int tx = threadIdx.x & 31, tg = threadIdx.x >> 5;
    #pragma unroll
    for (int rr = 0; rr < 4; rr++) {
        int ty = tg * 4 + rr;
        tile[ty][tx] = W1[(size_t)(k0 + ty) * HIDV + n0 + tx];
    }
    __syncthreads();
    #pragma unroll
    for (int rr = 0; rr < 4; rr++) {
        int ty = tg * 4 + rr;
        W1qT[(size_t)(n0 + ty) * DIMQ + k0 + tx] = f2bf(tile[tx][ty]);
    }
    if (blockIdx.x < 2) {
        int h = blockIdx.x * 256 + threadIdx.x;
        float acc = b1[h];
        #pragma unroll 8
        for (int k = 0; k < DIMZ; k++) acc += z[k] * W1[(size_t)(DIMQ + k) * HIDV + h];
        cvec[h] = acc;
    }
}

// Per batch row b (128 threads, 4 elems each): closed-form offline, 10-step online
// scan, bf16 GEMM inputs, F-base (K + V_quad + b2) written directly into out.
__global__ __launch_bounds__(128) void k_states(
        const float* __restrict__ u, const float* __restrict__ q0off,
        const float* __restrict__ p0off, const float* __restrict__ q0on,
        const float* __restrict__ p0on, const float* __restrict__ b2,
        unsigned short* __restrict__ Qall, float* __restrict__ out,
        float* __restrict__ qtraj,
        float R00, float R01, float R10, float R11) {
    int b = blockIdx.x, t = threadIdx.x;
    int j = t * 4;
    size_t idx = (size_t)b * DIMQ + j;
    float q[4], p[4], qo[4], po[4];
    *(float4*)q  = *(const float4*)(q0off + idx);
    *(float4*)p  = *(const float4*)(p0off + idx);
    *(float4*)qo = *(const float4*)(q0on + idx);
    *(float4*)po = *(const float4*)(p0on + idx);

    float sums[8] = {0, 0, 0, 0, 0, 0, 0, 0};
    us4 w0, w1, w2, w3;
    float q2[4], p2[4];
    #pragma unroll
    for (int c = 0; c < 4; c++) {
        float qq = q[c], pp = p[c];
        sums[0] += qq * qq;
        sums[1] += pp * pp;
        float qf = R00 * qq + R01 * pp;
        float pf = R10 * qq + R11 * pp;
        sums[2] += qf * qf;
        sums[3] += pf * pf;
        w0[c] = f2bf(qq);
        w1[c] = f2bf(qf);
        q2[c] = qo[c]; p2[c] = po[c];
        sums[4] += q2[c] * q2[c];
        sums[5] += p2[c] * p2[c];
        w2[c] = f2bf(q2[c]);
    }
    *(us4*)(Qall + idx) = w0;
    *(us4*)(Qall + (size_t)(BB + b) * DIMQ + j) = w1;
    *(us4*)(Qall + (size_t)(2 * BB + b) * DIMQ + j) = w2;

    const float* ub = u + (size_t)b * SS * DIMU + j;
    #pragma unroll
    for (int st = 0; st < 10; st++) {
        float uv[4];
        *(float4*)uv = *(const float4*)(ub + (size_t)st * DIMU);
        #pragma unroll
        for (int c = 0; c < 4; c++) {
            p2[c] = (p2[c] - 0.1f * (0.1f * q2[c]) + 0.1f * (0.1f * uv[c])) * 0.99f;
            q2[c] = q2[c] + 0.1f * p2[c];
        }
    }
    #pragma unroll
    for (int c = 0; c < 4; c++) {
        sums[6] += q2[c] * q2[c];
        sums[7] += p2[c] * p2[c];
        w3[c] = f2bf(q2[c]);
    }
    *(us4*)(Qall + (size_t)(3 * BB + b) * DIMQ + j) = w3;
    *(float4*)(qtraj + idx) = *(float4*)q2;

    __shared__ float red[2][8];
    int lane = t & 63, w = t >> 6;
    #pragma unroll
    for (int k = 0; k < 8; k++) {
        float v = sums[k];
        #pragma unroll
        for (int m = 1; m < 64; m <<= 1) v += __shfl_xor(v, m, 64);
        if (lane == 0) red[w][k] = v;
    }
    __syncthreads();
    if (t < 4) {
        int e = t;
        float sq = red[0][2 * e] + red[1][2 * e];
        float sp = red[0][2 * e + 1] + red[1][2 * e + 1];
        float F = 0.5f * sp + 0.05f * sq + b2[0];
        size_t o = (size_t)b * 2 + (e & 1) + (size_t)(e >> 1) * 2 * BB;
        out[o] = F;  // GEMM atomicAdds V_net partials on top
    }
}

// GEMM: Qall(16384x512 bf16) @ W1qT^T with fused tanh(.+c)*W2 reduce-over-N
// epilogue -> atomicAdd into out. 128x128 tile, 2-phase double-buffered LDS,
// XOR-swizzled (pre-swizzled global source + swizzled ds_read).
__global__ __launch_bounds__(256) void k_gemm(
        const unsigned short* __restrict__ Qall, const unsigned short* __restrict__ W1qT,
        const float* __restrict__ cvec, const float* __restrict__ W2,
        float* __restrict__ out) {
    __shared__ __attribute__((aligned(16))) char lds[65536];
    const int t = threadIdx.x;
    const int lane = t & 63;
    const int w = t >> 6;
    const int wr = w >> 1, wc = w & 1;
    const int rowBase = blockIdx.x * 128;
    const int colBase = blockIdx.y * 128;

    f32x4 acc[4][4] = {};

    auto STAGE = [&](int kt, int buf) {
        char* ldsA = lds + buf * 32768;
        char* ldsB = ldsA + 16384;
        #pragma unroll
        for (int i = 0; i < 4; i++) {
            unsigned chunk = i * 256 + t;      // 0..1023, 16B each
            unsigned r = chunk >> 3;           // row 0..127
            unsigned scb = (chunk & 7) ^ (r & 7);
            const unsigned short* srcA = Qall + (size_t)(rowBase + r) * 512 + (unsigned)kt * 64 + scb * 8;
            __builtin_amdgcn_global_load_lds(
                (const __attribute__((address_space(1))) unsigned int*)(const void*)srcA,
                (__attribute__((address_space(3))) unsigned int*)(void*)(ldsA + chunk * 16), 16, 0, 0);
            const unsigned short* srcB = W1qT + (size_t)(colBase + r) * 512 + (unsigned)kt * 64 + scb * 8;
            __builtin_amdgcn_global_load_lds(
                (const __attribute__((address_space(1))) unsigned int*)(const void*)srcB,
                (__attribute__((address_space(3))) unsigned int*)(void*)(ldsB + chunk * 16), 16, 0, 0);
        }
    };

    STAGE(0, 0);
    asm volatile("s_waitcnt vmcnt(0)" ::: "memory");
    __builtin_amdgcn_s_barrier();

    for (int kt = 0; kt < 8; kt++) {
        int cur = kt & 1;
        if (kt < 7) STAGE(kt + 1, cur ^ 1);
        char* ldsA = lds + cur * 32768;
        char* ldsB = ldsA + 16384;
        #pragma unroll
        for (int ks = 0; ks < 2; ks++) {
            sh8 af[4], bf_[4];
            int kb = ks * 64 + ((lane >> 4) << 4);
            #pragma unroll
            for (int mi = 0; mi < 4; mi++) {
                int m = wr * 64 + mi * 16 + (lane & 15);
                af[mi] = *(const sh8*)(ldsA + m * 128 + (kb ^ ((m & 7) << 4)));
            }
            #pragma unroll
            for (int ni = 0; ni < 4; ni++) {
                int n = wc * 64 + ni * 16 + (lane & 15);
                bf_[ni] = *(const sh8*)(ldsB + n * 128 + (kb ^ ((n & 7) << 4)));
            }
            #pragma unroll
            for (int mi = 0; mi < 4; mi++)
                #pragma unroll
                for (int ni = 0; ni < 4; ni++)
                    acc[mi][ni] = __builtin_amdgcn_mfma_f32_16x16x32_bf16(af[mi], bf_[ni], acc[mi][ni], 0, 0, 0);
        }
        asm volatile("s_waitcnt vmcnt(0) lgkmcnt(0)" ::: "memory");
        __builtin_amdgcn_s_barrier();
    }

    // epilogue: out[row] += sum_n tanh(acc + c[n]) * W2[n]
    float w2v[4], cv[4];
    #pragma unroll
    for (int ni = 0; ni < 4; ni++) {
        int n = colBase + wc * 64 + ni * 16 + (lane & 15);
        w2v[ni] = W2[n];
        cv[ni] = cvec[n];
    }
    #pragma unroll
    for (int mi = 0; mi < 4; mi++) {
        #pragma unroll
        for (int r = 0; r < 4; r++) {
            float partial = 0.f;
            #pragma unroll
            for (int ni = 0; ni < 4; ni++)
                partial += tanhf(acc[mi][ni][r] + cv[ni]) * w2v[ni];
            partial += __shfl_xor(partial, 1, 64);
            partial += __shfl_xor(partial, 2, 64);
            partial += __shfl_xor(partial, 4, 64);
            partial += __shfl_xor(partial, 8, 64);
            if ((lane & 15) == 0) {
                int row = rowBase + wr * 64 + mi * 16 + ((lane >> 4) << 2) + r;
                int e = row >> 12, bb = row & 4095;
                size_t o = (size_t)bb * 2 + (e & 1) + (size_t)(e >> 1) * 2 * BB;
                atomicAdd(out + o, partial);
            }
        }
    }
}

extern "C" void kernel_launch(void* const* d_in, const int* in_sizes, int n_in,
                              void* d_out, int out_size, void* d_ws, size_t ws_size,
                              hipStream_t stream) {
    const float* u     = (const float*)d_in[0];
    const float* q0off = (const float*)d_in[1];
    const float* p0off = (const float*)d_in[2];
    const float* q0on  = (const float*)d_in[3];
    const float* p0on  = (const float*)d_in[4];
    const float* z     = (const float*)d_in[5];
    const float* W1    = (const float*)d_in[6];
    const float* b1    = (const float*)d_in[7];
    const float* W2    = (const float*)d_in[8];
    const float* b2    = (const float*)d_in[9];
    float* out = (float*)d_out;

    char* ws = (char*)d_ws;
    unsigned short* Qall = (unsigned short*)ws;                // 16 MB
    unsigned short* W1qT = (unsigned short*)(ws + 16777216);   // 512 KB
    float* cvec = (float*)(ws + 16777216 + 524288);            // 2 KB

    // offline propagator M^19 (double): q' = q + 0.1 p ; p' = 0.99 p - 0.0099 q
    double a00 = 1, a01 = 0, a10 = 0, a11 = 1;
    const double m00 = 1.0, m01 = 0.1, m10 = -0.1 * 0.1 * 0.99, m11 = 0.99;
    for (int i = 0; i < 19; i++) {
        double n00 = m00 * a00 + m01 * a10;
        double n01 = m00 * a01 + m01 * a11;
        double n10 = m10 * a00 + m11 * a10;
        double n11 = m10 * a01 + m11 * a11;
        a00 = n00; a01 = n01; a10 = n10; a11 = n11;
    }

    k_prep<<<256, 256, 0, stream>>>(W1, z, b1, W1qT, cvec);
    k_states<<<BB, 128, 0, stream>>>(u, q0off, p0off, q0on, p0on, b2, Qall, out,
                                     out + 4 * BB, (float)a00, (float)a01, (float)a10, (float)a11);
    k_gemm<<<dim3(128, 4), 256, 0, stream>>>(Qall, W1qT, cvec, W2, out);
}